// Round 2
// baseline (5862.646 us; speedup 1.0000x reference)
//
#include <hip/hip_runtime.h>
#include <math.h>

#define UNITS   128
#define NRBF    10
#define SBF     9
#define NLAYERS 3
#define NELEM   95
#define NTOTAL  60000
#define NLOCAL  50000
#define NGHOST  10000
#define NEDGE   250000
#define NTRIPLE 1000000
#define CUTOFF  5.0f
#define TBCUT   4.0f
#define PI_F    3.14159265358979323846f

__device__ __forceinline__ float sigm(float x){ return 1.0f/(1.0f+expf(-x)); }
__device__ __forceinline__ float silu(float x){ return x/(1.0f+expf(-x)); }
__device__ __forceinline__ float polycut(float r){
    float q = r*(1.0f/TBCUT);
    float q2 = q*q, q3 = q2*q;
    float p = 1.0f - 6.0f*q2*q3 + 15.0f*q2*q2 - 10.0f*q3;
    return (r <= TBCUT) ? p : 0.0f;
}

__device__ __forceinline__ void fma4s(float4& acc, float s, const float4& v){
    acc.x = fmaf(s, v.x, acc.x);
    acc.y = fmaf(s, v.y, acc.y);
    acc.z = fmaf(s, v.z, acc.z);
    acc.w = fmaf(s, v.w, acc.w);
}

// ---------------- edge geometry + rbf ----------------
__global__ void k_edge_geom(const float* __restrict__ pos, const float* __restrict__ cell,
                            const float* __restrict__ pbc, const int* __restrict__ src,
                            const int* __restrict__ dst, const int* __restrict__ batch,
                            float* __restrict__ evec, float* __restrict__ elen,
                            float* __restrict__ rbf0){
    int e = blockIdx.x*blockDim.x + threadIdx.x;
    if (e >= NEDGE) return;
    int s = src[e], d = dst[e];
    int b = batch[s];
    const float* C = cell + b*9;
    float p0 = pbc[e*3+0], p1 = pbc[e*3+1], p2 = pbc[e*3+2];
    float vx = pos[s*3+0] - (pos[d*3+0] + p0*C[0] + p1*C[3] + p2*C[6]);
    float vy = pos[s*3+1] - (pos[d*3+1] + p0*C[1] + p1*C[4] + p2*C[7]);
    float vz = pos[s*3+2] - (pos[d*3+2] + p0*C[2] + p1*C[5] + p2*C[8]);
    float r = sqrtf(vx*vx + vy*vy + vz*vz);
    evec[e*3+0] = vx; evec[e*3+1] = vy; evec[e*3+2] = vz;
    elen[e] = r;
    #pragma unroll
    for (int i = 0; i < NRBF; i++){
        float mu = (CUTOFF/(NRBF-1))*i;
        float dm = r - mu;
        rbf0[e*NRBF + i] = expf(-dm*dm*2.0f);
    }
}

// ---------------- atom embedding gather ----------------
__global__ void k_embed(const int* __restrict__ anum, const float* __restrict__ embw,
                        float* __restrict__ A){
    int t = blockIdx.x*blockDim.x + threadIdx.x;
    if (t >= NTOTAL*32) return;
    int a = t >> 5, q = t & 31;
    ((float4*)A)[t] = ((const float4*)embw)[anum[a]*32 + q];
}

// ---------------- edge encoding: E = rbf0 @ Wenc + benc ----------------
__global__ void k_edge_enc(const float* __restrict__ rbf0, const float* __restrict__ encw,
                           const float* __restrict__ encb, float* __restrict__ E){
    int t = blockIdx.x*blockDim.x + threadIdx.x;
    if (t >= NEDGE*32) return;
    int e = t >> 5, q = t & 31;
    float4 acc = ((const float4*)encb)[q];
    const float4* W4 = (const float4*)encw;
    #pragma unroll
    for (int r = 0; r < NRBF; r++){
        float rv = rbf0[e*NRBF + r];
        fma4s(acc, rv, W4[r*32 + q]);
    }
    ((float4*)E)[t] = acc;
}

// ---------------- per-layer: atom sbf mlp (sigmoid(A[:nlocal] @ W + b)) ----------------
__global__ void k_tb_mlp(const float* __restrict__ A, const float* __restrict__ W,
                         const float* __restrict__ b, float* __restrict__ out){
    int a = blockIdx.x*blockDim.x + threadIdx.x;
    if (a >= NLOCAL) return;
    float acc[SBF];
    #pragma unroll
    for (int s = 0; s < SBF; s++) acc[s] = b[s];
    const float4* row4 = (const float4*)(A + (size_t)a*UNITS);
    for (int k4 = 0; k4 < 32; k4++){
        float4 v = row4[k4];
        const float* w = W + (k4*4)*SBF;
        #pragma unroll
        for (int s = 0; s < SBF; s++){
            acc[s] = fmaf(v.x, w[s],        acc[s]);
            acc[s] = fmaf(v.y, w[s+SBF],    acc[s]);
            acc[s] = fmaf(v.z, w[s+2*SBF],  acc[s]);
            acc[s] = fmaf(v.w, w[s+3*SBF],  acc[s]);
        }
    }
    #pragma unroll
    for (int s = 0; s < SBF; s++) out[a*SBF + s] = sigm(acc[s]);
}

// ---------------- per-layer: triples -> scatter into tb_out ----------------
__global__ void k_triple(const float* __restrict__ evec, const float* __restrict__ elen,
                         const int* __restrict__ esrc, const int* __restrict__ tbi,
                         const float* __restrict__ amlp, float* __restrict__ tb_out){
    int t = blockIdx.x*blockDim.x + threadIdx.x;
    if (t >= NTRIPLE) return;
    int ij = tbi[2*t], ik = tbi[2*t+1];
    float rij = elen[ij], rik = elen[ik];
    float cutij = polycut(rij), cutik = polycut(rik);
    float cc = cutij*cutik;
    if (cc == 0.0f) return;   // exact zero contribution (r > 4 on either edge)
    float ax = evec[ij*3+0], ay = evec[ij*3+1], az = evec[ij*3+2];
    float bx = evec[ik*3+0], by = evec[ik*3+1], bz = evec[ik*3+2];
    float dot = ax*bx + ay*by + az*bz;
    float c = dot/(rij*rik + 1e-12f);
    c = fminf(fmaxf(c, -1.0f + 1e-7f), 1.0f - 1e-7f);
    // ang = cos(l*theta) = {1, c, 2c^2-1}
    float a0 = 1.0f, a1 = c, a2 = 2.0f*c*c - 1.0f;
    // rad = sin(n*pi*r/4)/(r+1e-6), n=1..3 via multiple angles
    float x = rik*(PI_F/TBCUT);
    float s1, c1;
    sincosf(x, &s1, &c1);
    float s2 = 2.0f*s1*c1;
    float s3 = s1*(3.0f - 4.0f*s1*s1);
    float inv = 1.0f/(rik + 1e-6f);
    float r0 = s1*inv, r1 = s2*inv, r2 = s3*inv;
    int ka = esrc[ik];
    const float* am = amlp + (size_t)ka*SBF;
    float* dst = tb_out + (size_t)ij*SBF;
    atomicAdd(dst+0, r0*a0*am[0]*cc);
    atomicAdd(dst+1, r0*a1*am[1]*cc);
    atomicAdd(dst+2, r0*a2*am[2]*cc);
    atomicAdd(dst+3, r1*a0*am[3]*cc);
    atomicAdd(dst+4, r1*a1*am[4]*cc);
    atomicAdd(dst+5, r1*a2*am[5]*cc);
    atomicAdd(dst+6, r2*a0*am[6]*cc);
    atomicAdd(dst+7, r2*a1*am[7]*cc);
    atomicAdd(dst+8, r2*a2*am[8]*cc);
}

// ---------------- fused gather + gated MLP GEMM ----------------
// MODE 0: edge step (ge):  stages E+tb into feat, writes E_new = E_tb + gated*el
// MODE 1: atom step (ga):  stages E, atomically adds gated*el into agg[src]
template<int MODE>
__global__ __launch_bounds__(256, 3)
void k_gated(const float* __restrict__ A, float* __restrict__ E,
             const int* __restrict__ esrc, const int* __restrict__ edst,
             const float* __restrict__ tb_out, const float* __restrict__ tbg,
             const float* __restrict__ tbb,
             const float* __restrict__ Wm, const float* __restrict__ bm,
             const float* __restrict__ Wg, const float* __restrict__ bg,
             const float* __restrict__ elw, const float* __restrict__ elb,
             const float* __restrict__ rbf0, float* __restrict__ agg){
    __shared__ float4 feat4[32*98];   // 32 rows x 96 quads, padded stride 98
    __shared__ float  rbf_s[32][NRBF];
    __shared__ float  tb_s[32][SBF];
    __shared__ int    src_s[32];
    __shared__ int    dst_s[32];

    const int tid = threadIdx.x;
    const int e0  = blockIdx.x*32;

    if (tid < 32){
        int e = min(e0 + tid, NEDGE-1);
        src_s[tid] = esrc[e];
        dst_s[tid] = edst[e];
        #pragma unroll
        for (int r = 0; r < NRBF; r++) rbf_s[tid][r] = rbf0[(size_t)e*NRBF + r];
        if (MODE == 0){
            #pragma unroll
            for (int s = 0; s < SBF; s++) tb_s[tid][s] = tb_out[(size_t)e*SBF + s];
        }
    }
    __syncthreads();

    const float4* A4   = (const float4*)A;
    const float4* E4   = (const float4*)E;
    const float4* tbg4 = (const float4*)tbg;
    const float4* tbb4 = (const float4*)tbb;

    // stage feat tile: 32 rows x 96 float4 = 3072, 12 per thread
    #pragma unroll
    for (int j = 0; j < 12; j++){
        int idx = j*256 + tid;
        int m   = idx/96;
        int k4  = idx - m*96;
        float4 v;
        if (k4 < 32){
            v = A4[(size_t)src_s[m]*32 + k4];
        } else if (k4 < 64){
            v = A4[(size_t)dst_s[m]*32 + (k4-32)];
        } else {
            int q = k4 - 64;
            int e = min(e0 + m, NEDGE-1);
            v = E4[(size_t)e*32 + q];
            if (MODE == 0){
                float4 tacc = tbb4[q];
                #pragma unroll
                for (int s = 0; s < SBF; s++){
                    fma4s(tacc, tb_s[m][s], tbg4[s*32 + q]);
                }
                v.x += tacc.x; v.y += tacc.y; v.z += tacc.z; v.w += tacc.w;
            }
        }
        feat4[m*98 + k4] = v;
    }
    __syncthreads();

    const int quad = tid & 31;
    const int sub  = tid >> 5;
    const float4* Wm4 = (const float4*)Wm;
    const float4* Wg4 = (const float4*)Wg;

    float4 am[4], ag[4];
    #pragma unroll
    for (int i = 0; i < 4; i++){
        am[i] = make_float4(0.f,0.f,0.f,0.f);
        ag[i] = make_float4(0.f,0.f,0.f,0.f);
    }

    const float4* frow = feat4 + sub*4*98;
    for (int k4 = 0; k4 < 96; k4++){
        float4 f0 = frow[k4];
        float4 f1 = frow[98 + k4];
        float4 f2 = frow[196 + k4];
        float4 f3 = frow[294 + k4];
        int kb = k4*4;
        float4 wm0 = Wm4[(kb+0)*32 + quad];
        float4 wm1 = Wm4[(kb+1)*32 + quad];
        float4 wm2 = Wm4[(kb+2)*32 + quad];
        float4 wm3 = Wm4[(kb+3)*32 + quad];
        float4 wg0 = Wg4[(kb+0)*32 + quad];
        float4 wg1 = Wg4[(kb+1)*32 + quad];
        float4 wg2 = Wg4[(kb+2)*32 + quad];
        float4 wg3 = Wg4[(kb+3)*32 + quad];
        fma4s(am[0], f0.x, wm0); fma4s(am[0], f0.y, wm1); fma4s(am[0], f0.z, wm2); fma4s(am[0], f0.w, wm3);
        fma4s(am[1], f1.x, wm0); fma4s(am[1], f1.y, wm1); fma4s(am[1], f1.z, wm2); fma4s(am[1], f1.w, wm3);
        fma4s(am[2], f2.x, wm0); fma4s(am[2], f2.y, wm1); fma4s(am[2], f2.z, wm2); fma4s(am[2], f2.w, wm3);
        fma4s(am[3], f3.x, wm0); fma4s(am[3], f3.y, wm1); fma4s(am[3], f3.z, wm2); fma4s(am[3], f3.w, wm3);
        fma4s(ag[0], f0.x, wg0); fma4s(ag[0], f0.y, wg1); fma4s(ag[0], f0.z, wg2); fma4s(ag[0], f0.w, wg3);
        fma4s(ag[1], f1.x, wg0); fma4s(ag[1], f1.y, wg1); fma4s(ag[1], f1.z, wg2); fma4s(ag[1], f1.w, wg3);
        fma4s(ag[2], f2.x, wg0); fma4s(ag[2], f2.y, wg1); fma4s(ag[2], f2.z, wg2); fma4s(ag[2], f2.w, wg3);
        fma4s(ag[3], f3.x, wg0); fma4s(ag[3], f3.y, wg1); fma4s(ag[3], f3.z, wg2); fma4s(ag[3], f3.w, wg3);
    }

    const float4* elw4 = (const float4*)elw;
    float4 bmv  = ((const float4*)bm)[quad];
    float4 bgv  = ((const float4*)bg)[quad];
    float4 elbv = ((const float4*)elb)[quad];

    #pragma unroll
    for (int i = 0; i < 4; i++){
        int m = sub*4 + i;
        int e = e0 + m;
        if (e >= NEDGE) continue;
        float4 el = elbv;
        #pragma unroll
        for (int r = 0; r < NRBF; r++){
            fma4s(el, rbf_s[m][r], elw4[r*32 + quad]);
        }
        float4 xm, xg, g;
        xm.x = am[i].x + bmv.x; xm.y = am[i].y + bmv.y; xm.z = am[i].z + bmv.z; xm.w = am[i].w + bmv.w;
        xg.x = ag[i].x + bgv.x; xg.y = ag[i].y + bgv.y; xg.z = ag[i].z + bgv.z; xg.w = ag[i].w + bgv.w;
        g.x = silu(xm.x)*sigm(xg.x);
        g.y = silu(xm.y)*sigm(xg.y);
        g.z = silu(xm.z)*sigm(xg.z);
        g.w = silu(xm.w)*sigm(xg.w);
        if (MODE == 0){
            float4 base = feat4[m*98 + 64 + quad];
            float4 o;
            o.x = base.x + g.x*el.x;
            o.y = base.y + g.y*el.y;
            o.z = base.z + g.z*el.z;
            o.w = base.w + g.w*el.w;
            ((float4*)E)[(size_t)e*32 + quad] = o;
        } else {
            float* p = agg + (size_t)src_s[m]*UNITS + quad*4;
            atomicAdd(p+0, g.x*el.x);
            atomicAdd(p+1, g.y*el.y);
            atomicAdd(p+2, g.z*el.z);
            atomicAdd(p+3, g.w*el.w);
        }
    }
}

// ---------------- ghost expansion: A = concat(agg, agg[ghost_map]) ----------------
__global__ void k_expand(const float* __restrict__ agg, const int* __restrict__ gmap,
                         float* __restrict__ A){
    int t = blockIdx.x*blockDim.x + threadIdx.x;
    if (t >= NTOTAL*32) return;
    int i = t >> 5, q = t & 31;
    int row = (i < NLOCAL) ? i : gmap[i - NLOCAL];
    ((float4*)A)[t] = ((const float4*)agg)[(size_t)row*32 + q];
}

// ---------------- final readout + global sum ----------------
__global__ void k_final(const float* __restrict__ A, const float* __restrict__ W1,
                        const float* __restrict__ b1, const float* __restrict__ W2,
                        const float* __restrict__ b2, const int* __restrict__ anum,
                        const float* __restrict__ escl, const float* __restrict__ eshf,
                        float* __restrict__ out){
    __shared__ float red[256];
    const int tid  = threadIdx.x;
    const int c    = tid & 127;
    const int half = tid >> 7;
    float b1c = b1[c];
    float w2c = W2[c];
    float b2v = b2[0];
    float tpart = 0.0f;
    const int npairs = NLOCAL/2;
    for (int p = blockIdx.x; p < npairs; p += gridDim.x){
        int a = 2*p + half;
        const float* h = A + (size_t)a*UNITS;
        float acc = b1c;
        for (int k = 0; k < UNITS; k++)
            acc = fmaf(h[k], W1[k*UNITS + c], acc);
        float hid = silu(acc);
        int z = anum[a];
        float sc = escl[z];
        tpart = fmaf(sc*hid, w2c, tpart);
        if (c == 0) tpart += sc*b2v + eshf[z];
    }
    red[tid] = tpart;
    __syncthreads();
    for (int s = 128; s > 0; s >>= 1){
        if (tid < s) red[tid] += red[tid + s];
        __syncthreads();
    }
    if (tid == 0) atomicAdd(out, red[0]);
}

extern "C" void kernel_launch(void* const* d_in, const int* in_sizes, int n_in,
                              void* d_out, int out_size, void* d_ws, size_t ws_size,
                              hipStream_t stream){
    const int*   anum  = (const int*)d_in[0];
    const float* pos   = (const float*)d_in[1];
    const float* cell  = (const float*)d_in[2];
    const float* pbc   = (const float*)d_in[3];
    const int*   esrc  = (const int*)d_in[4];
    const int*   edst  = (const int*)d_in[5];
    const int*   tbi   = (const int*)d_in[6];
    const int*   batch = (const int*)d_in[7];
    const int*   gmap  = (const int*)d_in[8];
    const float* embw  = (const float*)d_in[10];
    const float* encw  = (const float*)d_in[11];
    const float* encb  = (const float*)d_in[12];
    const float* tbaw  = (const float*)d_in[13];
    const float* tbab  = (const float*)d_in[14];
    const float* tbgw  = (const float*)d_in[15];
    const float* tbgb  = (const float*)d_in[16];
    const float* gewm  = (const float*)d_in[17];
    const float* gebm  = (const float*)d_in[18];
    const float* gewg  = (const float*)d_in[19];
    const float* gebg  = (const float*)d_in[20];
    const float* elew  = (const float*)d_in[21];
    const float* eleb  = (const float*)d_in[22];
    const float* gawm  = (const float*)d_in[23];
    const float* gabm  = (const float*)d_in[24];
    const float* gawg  = (const float*)d_in[25];
    const float* gabg  = (const float*)d_in[26];
    const float* elaw  = (const float*)d_in[27];
    const float* elab  = (const float*)d_in[28];
    const float* fw1   = (const float*)d_in[29];
    const float* fb1   = (const float*)d_in[30];
    const float* fw2   = (const float*)d_in[31];
    const float* fb2   = (const float*)d_in[32];
    const float* escl  = (const float*)d_in[33];
    const float* eshf  = (const float*)d_in[34];
    (void)in_sizes; (void)n_in; (void)out_size; (void)ws_size;

    float* ws    = (float*)d_ws;
    float* atomA = ws;                                   // NTOTAL*128
    float* agg   = atomA + (size_t)NTOTAL*UNITS;         // NLOCAL*128
    float* edgeE = agg   + (size_t)NLOCAL*UNITS;         // NEDGE*128
    float* evec  = edgeE + (size_t)NEDGE*UNITS;          // NEDGE*3
    float* elen  = evec  + (size_t)NEDGE*3;              // NEDGE
    float* rbf0  = elen  + (size_t)NEDGE;                // NEDGE*10
    float* tbout = rbf0  + (size_t)NEDGE*NRBF;           // NEDGE*9
    float* amlp  = tbout + (size_t)NEDGE*SBF;            // NLOCAL*9

    float* out = (float*)d_out;
    hipMemsetAsync(out, 0, sizeof(float), stream);

    k_edge_geom<<<(NEDGE+255)/256, 256, 0, stream>>>(pos, cell, pbc, esrc, edst, batch,
                                                     evec, elen, rbf0);
    k_embed<<<(NTOTAL*32+255)/256, 256, 0, stream>>>(anum, embw, atomA);
    k_edge_enc<<<(NEDGE*32+255)/256, 256, 0, stream>>>(rbf0, encw, encb, edgeE);

    const int gemm_blocks = (NEDGE+31)/32;
    for (int L = 0; L < NLAYERS; L++){
        k_tb_mlp<<<(NLOCAL+255)/256, 256, 0, stream>>>(atomA,
            tbaw + (size_t)L*UNITS*SBF, tbab + (size_t)L*SBF, amlp);
        hipMemsetAsync(tbout, 0, (size_t)NEDGE*SBF*sizeof(float), stream);
        k_triple<<<(NTRIPLE+255)/256, 256, 0, stream>>>(evec, elen, esrc, tbi, amlp, tbout);
        hipMemcpyAsync(agg, atomA, (size_t)NLOCAL*UNITS*sizeof(float),
                       hipMemcpyDeviceToDevice, stream);
        k_gated<0><<<gemm_blocks, 256, 0, stream>>>(atomA, edgeE, esrc, edst,
            tbout, tbgw + (size_t)L*SBF*UNITS, tbgb + (size_t)L*UNITS,
            gewm + (size_t)L*3*UNITS*UNITS, gebm + (size_t)L*UNITS,
            gewg + (size_t)L*3*UNITS*UNITS, gebg + (size_t)L*UNITS,
            elew + (size_t)L*NRBF*UNITS, eleb + (size_t)L*UNITS, rbf0, nullptr);
        k_gated<1><<<gemm_blocks, 256, 0, stream>>>(atomA, edgeE, esrc, edst,
            nullptr, nullptr, nullptr,
            gawm + (size_t)L*3*UNITS*UNITS, gabm + (size_t)L*UNITS,
            gawg + (size_t)L*3*UNITS*UNITS, gabg + (size_t)L*UNITS,
            elaw + (size_t)L*NRBF*UNITS, elab + (size_t)L*UNITS, rbf0, agg);
        if (L < NLAYERS-1)
            k_expand<<<(NTOTAL*32+255)/256, 256, 0, stream>>>(agg, gmap, atomA);
    }
    k_final<<<1024, 256, 0, stream>>>(agg, fw1, fb1, fw2, fb2, anum, escl, eshf, out);
}

// Round 3
// 1777.553 us; speedup vs baseline: 3.2982x; 3.2982x over previous
//
#include <hip/hip_runtime.h>
#include <math.h>

#define UNITS   128
#define NRBF    10
#define SBF     9
#define NLAYERS 3
#define NELEM   95
#define NTOTAL  60000
#define NLOCAL  50000
#define NGHOST  10000
#define NEDGE   250000
#define NTRIPLE 1000000
#define CUTOFF  5.0f
#define TBCUT   4.0f
#define PI_F    3.14159265358979323846f

typedef __attribute__((ext_vector_type(8))) short short8;
typedef __attribute__((ext_vector_type(4))) float f32x4;

__device__ __forceinline__ float sigm(float x){ return 1.0f/(1.0f+expf(-x)); }
__device__ __forceinline__ float silu(float x){ return x/(1.0f+expf(-x)); }
__device__ __forceinline__ float polycut(float r){
    float q = r*(1.0f/TBCUT);
    float q2 = q*q, q3 = q2*q;
    float p = 1.0f - 6.0f*q2*q3 + 15.0f*q2*q2 - 10.0f*q3;
    return (r <= TBCUT) ? p : 0.0f;
}
__device__ __forceinline__ ushort f2bf(float x){
    unsigned u = __float_as_uint(x);
    unsigned r = (u + 0x7fffu + ((u>>16)&1u)) >> 16;
    return (ushort)r;
}
__device__ __forceinline__ void fma4s(float4& acc, float s, const float4& v){
    acc.x = fmaf(s, v.x, acc.x);
    acc.y = fmaf(s, v.y, acc.y);
    acc.z = fmaf(s, v.z, acc.z);
    acc.w = fmaf(s, v.w, acc.w);
}

// ---------------- edge geometry + rbf ----------------
__global__ void k_edge_geom(const float* __restrict__ pos, const float* __restrict__ cell,
                            const float* __restrict__ pbc, const int* __restrict__ src,
                            const int* __restrict__ dst, const int* __restrict__ batch,
                            float* __restrict__ evec, float* __restrict__ elen,
                            float* __restrict__ rbf0){
    int e = blockIdx.x*blockDim.x + threadIdx.x;
    if (e >= NEDGE) return;
    int s = src[e], d = dst[e];
    int b = batch[s];
    const float* C = cell + b*9;
    float p0 = pbc[e*3+0], p1 = pbc[e*3+1], p2 = pbc[e*3+2];
    float vx = pos[s*3+0] - (pos[d*3+0] + p0*C[0] + p1*C[3] + p2*C[6]);
    float vy = pos[s*3+1] - (pos[d*3+1] + p0*C[1] + p1*C[4] + p2*C[7]);
    float vz = pos[s*3+2] - (pos[d*3+2] + p0*C[2] + p1*C[5] + p2*C[8]);
    float r = sqrtf(vx*vx + vy*vy + vz*vz);
    evec[e*3+0] = vx; evec[e*3+1] = vy; evec[e*3+2] = vz;
    elen[e] = r;
    #pragma unroll
    for (int i = 0; i < NRBF; i++){
        float mu = (CUTOFF/(NRBF-1))*i;
        float dm = r - mu;
        rbf0[e*NRBF + i] = expf(-dm*dm*2.0f);
    }
}

// ---------------- atom embedding gather ----------------
__global__ void k_embed(const int* __restrict__ anum, const float* __restrict__ embw,
                        float* __restrict__ A){
    int t = blockIdx.x*blockDim.x + threadIdx.x;
    if (t >= NTOTAL*32) return;
    int a = t >> 5, q = t & 31;
    ((float4*)A)[t] = ((const float4*)embw)[anum[a]*32 + q];
}

// ---------------- edge encoding: E = rbf0 @ Wenc + benc ----------------
__global__ void k_edge_enc(const float* __restrict__ rbf0, const float* __restrict__ encw,
                           const float* __restrict__ encb, float* __restrict__ E){
    int t = blockIdx.x*blockDim.x + threadIdx.x;
    if (t >= NEDGE*32) return;
    int e = t >> 5, q = t & 31;
    float4 acc = ((const float4*)encb)[q];
    const float4* W4 = (const float4*)encw;
    #pragma unroll
    for (int r = 0; r < NRBF; r++){
        float rv = rbf0[e*NRBF + r];
        fma4s(acc, rv, W4[r*32 + q]);
    }
    ((float4*)E)[t] = acc;
}

// ---------------- pack gated-MLP weights into MFMA B-fragment layout ----------------
// layout: [L][mat(ge_m,ge_g,ga_m,ga_g)][kb:12][nt:8][lane:64][j:8] bf16
__global__ void k_pack_w(const float* __restrict__ gewm, const float* __restrict__ gewg,
                         const float* __restrict__ gawm, const float* __restrict__ gawg,
                         ushort* __restrict__ wp){
    int t = blockIdx.x*blockDim.x + threadIdx.x;
    if (t >= 3*4*12*8*64) return;
    int lane = t & 63;
    int nt   = (t>>6) & 7;
    int rest = t >> 9;
    int kb   = rest % 12;
    int r2   = rest / 12;
    int mat  = r2 & 3;
    int L    = r2 >> 2;
    const float* src;
    if      (mat == 0) src = gewm;
    else if (mat == 1) src = gewg;
    else if (mat == 2) src = gawm;
    else               src = gawg;
    src += (size_t)L*384*128;
    int n = nt*16 + (lane & 15);
    int kbase = kb*32 + (lane>>4)*8;
    ushort* dst = wp + (size_t)t*8;
    #pragma unroll
    for (int j = 0; j < 8; j++) dst[j] = f2bf(src[(size_t)(kbase+j)*128 + n]);
}

// ---------------- per-layer: atom sbf mlp ----------------
__global__ void k_tb_mlp(const float* __restrict__ A, const float* __restrict__ W,
                         const float* __restrict__ b, float* __restrict__ out){
    int a = blockIdx.x*blockDim.x + threadIdx.x;
    if (a >= NLOCAL) return;
    float acc[SBF];
    #pragma unroll
    for (int s = 0; s < SBF; s++) acc[s] = b[s];
    const float4* row4 = (const float4*)(A + (size_t)a*UNITS);
    for (int k4 = 0; k4 < 32; k4++){
        float4 v = row4[k4];
        const float* w = W + (k4*4)*SBF;
        #pragma unroll
        for (int s = 0; s < SBF; s++){
            acc[s] = fmaf(v.x, w[s],        acc[s]);
            acc[s] = fmaf(v.y, w[s+SBF],    acc[s]);
            acc[s] = fmaf(v.z, w[s+2*SBF],  acc[s]);
            acc[s] = fmaf(v.w, w[s+3*SBF],  acc[s]);
        }
    }
    #pragma unroll
    for (int s = 0; s < SBF; s++) out[a*SBF + s] = sigm(acc[s]);
}

// ---------------- per-layer: triples -> scatter into tb_out ----------------
__global__ void k_triple(const float* __restrict__ evec, const float* __restrict__ elen,
                         const int* __restrict__ esrc, const int* __restrict__ tbi,
                         const float* __restrict__ amlp, float* __restrict__ tb_out){
    int t = blockIdx.x*blockDim.x + threadIdx.x;
    if (t >= NTRIPLE) return;
    int ij = tbi[2*t], ik = tbi[2*t+1];
    float rij = elen[ij], rik = elen[ik];
    float cutij = polycut(rij), cutik = polycut(rik);
    float cc = cutij*cutik;
    if (cc == 0.0f) return;
    float ax = evec[ij*3+0], ay = evec[ij*3+1], az = evec[ij*3+2];
    float bx = evec[ik*3+0], by = evec[ik*3+1], bz = evec[ik*3+2];
    float dot = ax*bx + ay*by + az*bz;
    float c = dot/(rij*rik + 1e-12f);
    c = fminf(fmaxf(c, -1.0f + 1e-7f), 1.0f - 1e-7f);
    float a0 = 1.0f, a1 = c, a2 = 2.0f*c*c - 1.0f;
    float x = rik*(PI_F/TBCUT);
    float s1, c1;
    sincosf(x, &s1, &c1);
    float s2 = 2.0f*s1*c1;
    float s3 = s1*(3.0f - 4.0f*s1*s1);
    float inv = 1.0f/(rik + 1e-6f);
    float r0 = s1*inv, r1 = s2*inv, r2 = s3*inv;
    int ka = esrc[ik];
    const float* am = amlp + (size_t)ka*SBF;
    float* dst = tb_out + (size_t)ij*SBF;
    atomicAdd(dst+0, r0*a0*am[0]*cc);
    atomicAdd(dst+1, r0*a1*am[1]*cc);
    atomicAdd(dst+2, r0*a2*am[2]*cc);
    atomicAdd(dst+3, r1*a0*am[3]*cc);
    atomicAdd(dst+4, r1*a1*am[4]*cc);
    atomicAdd(dst+5, r1*a2*am[5]*cc);
    atomicAdd(dst+6, r2*a0*am[6]*cc);
    atomicAdd(dst+7, r2*a1*am[7]*cc);
    atomicAdd(dst+8, r2*a2*am[8]*cc);
}

// ---------------- fused gather + gated MLP via bf16 MFMA ----------------
// 32 edges/block, 256 threads (4 waves). feat = [A[src] | A[dst] | E(+tbgate)] bf16 in LDS.
// Wave w covers output cols [w*32, w*32+32) for both the m- and g-matrix.
// MODE 0: E[e] += tbgate + silu(m)*sigm(g)*el   MODE 1: agg[src] += silu(m)*sigm(g)*el
template<int MODE>
__global__ __launch_bounds__(256, 4)
void k_gated(const float* __restrict__ A, float* __restrict__ E,
             const int* __restrict__ esrc, const int* __restrict__ edst,
             const float* __restrict__ tb_out, const float* __restrict__ tbg,
             const float* __restrict__ tbb,
             const ushort* __restrict__ WmP, const ushort* __restrict__ WgP,
             const float* __restrict__ bm, const float* __restrict__ bg,
             const float* __restrict__ elw, const float* __restrict__ elb,
             const float* __restrict__ rbf0, float* __restrict__ agg){
    __shared__ __align__(16) ushort feat_s[32*392];   // 32 rows x 384 bf16, stride 392
    __shared__ float rbf_s[32][NRBF];
    __shared__ float tb_s[32][SBF];
    __shared__ int   src_s[32];
    __shared__ int   dst_s[32];

    const int tid = threadIdx.x;
    const int e0  = blockIdx.x*32;

    if (tid < 32){
        int e = min(e0 + tid, NEDGE-1);
        src_s[tid] = esrc[e];
        dst_s[tid] = edst[e];
        #pragma unroll
        for (int r = 0; r < NRBF; r++) rbf_s[tid][r] = rbf0[(size_t)e*NRBF + r];
        if (MODE == 0){
            #pragma unroll
            for (int s = 0; s < SBF; s++) tb_s[tid][s] = tb_out[(size_t)e*SBF + s];
        }
    }
    __syncthreads();

    const float4* A4   = (const float4*)A;
    const float4* E4   = (const float4*)E;
    const float4* tbg4 = (const float4*)tbg;
    const float4* tbb4 = (const float4*)tbb;

    // stage feat: 32 rows x 96 float4 -> bf16, 12 pieces/thread
    #pragma unroll
    for (int j = 0; j < 12; j++){
        int idx = j*256 + tid;
        int m   = idx/96;
        int k4  = idx - m*96;
        float4 v;
        if (k4 < 32){
            v = A4[(size_t)src_s[m]*32 + k4];
        } else if (k4 < 64){
            v = A4[(size_t)dst_s[m]*32 + (k4-32)];
        } else {
            int q = k4 - 64;
            int e = min(e0 + m, NEDGE-1);
            v = E4[(size_t)e*32 + q];
            if (MODE == 0){
                float4 tacc = tbb4[q];
                #pragma unroll
                for (int s = 0; s < SBF; s++) fma4s(tacc, tb_s[m][s], tbg4[s*32 + q]);
                v.x += tacc.x; v.y += tacc.y; v.z += tacc.z; v.w += tacc.w;
            }
        }
        ushort4 h;
        h.x = f2bf(v.x); h.y = f2bf(v.y); h.z = f2bf(v.z); h.w = f2bf(v.w);
        *(ushort4*)&feat_s[m*392 + k4*4] = h;
    }
    __syncthreads();

    const int lane = tid & 63;
    const int w    = tid >> 6;
    const int quad = lane >> 4;
    const int l15  = lane & 15;

    f32x4 zero4 = {0.f, 0.f, 0.f, 0.f};
    f32x4 accm[2][2], accg[2][2];           // [m-tile][col-tile]
    #pragma unroll
    for (int mt = 0; mt < 2; mt++)
        #pragma unroll
        for (int ct = 0; ct < 2; ct++){ accm[mt][ct] = zero4; accg[mt][ct] = zero4; }

    const ushort* a0p = feat_s + l15*392 + quad*8;
    const ushort* a1p = a0p + 16*392;

    for (int ks = 0; ks < 12; ks++){
        short8 a0 = *(const short8*)(a0p + ks*32);
        short8 a1 = *(const short8*)(a1p + ks*32);
        #pragma unroll
        for (int ct = 0; ct < 2; ct++){
            int nt = w*2 + ct;
            size_t boff = ((size_t)(ks*8 + nt)*64 + lane)*8;
            short8 b_m = *(const short8*)(WmP + boff);
            short8 b_g = *(const short8*)(WgP + boff);
            accm[0][ct] = __builtin_amdgcn_mfma_f32_16x16x32_bf16(a0, b_m, accm[0][ct], 0, 0, 0);
            accm[1][ct] = __builtin_amdgcn_mfma_f32_16x16x32_bf16(a1, b_m, accm[1][ct], 0, 0, 0);
            accg[0][ct] = __builtin_amdgcn_mfma_f32_16x16x32_bf16(a0, b_g, accg[0][ct], 0, 0, 0);
            accg[1][ct] = __builtin_amdgcn_mfma_f32_16x16x32_bf16(a1, b_g, accg[1][ct], 0, 0, 0);
        }
    }

    // hoist per-column weights
    float bmv[2], bgv[2], elbv[2], elwv[2][NRBF], tbbv[2], tbgv[2][SBF];
    #pragma unroll
    for (int ct = 0; ct < 2; ct++){
        int c = w*32 + ct*16 + l15;
        bmv[ct]  = bm[c];
        bgv[ct]  = bg[c];
        elbv[ct] = elb[c];
        #pragma unroll
        for (int r = 0; r < NRBF; r++) elwv[ct][r] = elw[r*UNITS + c];
        if (MODE == 0){
            tbbv[ct] = tbb[c];
            #pragma unroll
            for (int s = 0; s < SBF; s++) tbgv[ct][s] = tbg[s*UNITS + c];
        }
    }

    #pragma unroll
    for (int mt = 0; mt < 2; mt++){
        #pragma unroll
        for (int r = 0; r < 4; r++){
            int ml = mt*16 + quad*4 + r;
            int e  = e0 + ml;
            if (e >= NEDGE) continue;
            #pragma unroll
            for (int ct = 0; ct < 2; ct++){
                int c = w*32 + ct*16 + l15;
                float xm = accm[mt][ct][r] + bmv[ct];
                float xg = accg[mt][ct][r] + bgv[ct];
                float gate = silu(xm)*sigm(xg);
                float el = elbv[ct];
                #pragma unroll
                for (int rr = 0; rr < NRBF; rr++) el = fmaf(rbf_s[ml][rr], elwv[ct][rr], el);
                float v = gate*el;
                if (MODE == 0){
                    float tbc = tbbv[ct];
                    #pragma unroll
                    for (int s = 0; s < SBF; s++) tbc = fmaf(tb_s[ml][s], tbgv[ct][s], tbc);
                    E[(size_t)e*UNITS + c] += tbc + v;
                } else {
                    atomicAdd(&agg[(size_t)src_s[ml]*UNITS + c], v);
                }
            }
        }
    }
}

// ---------------- ghost expansion ----------------
__global__ void k_expand(const float* __restrict__ agg, const int* __restrict__ gmap,
                         float* __restrict__ A){
    int t = blockIdx.x*blockDim.x + threadIdx.x;
    if (t >= NTOTAL*32) return;
    int i = t >> 5, q = t & 31;
    int row = (i < NLOCAL) ? i : gmap[i - NLOCAL];
    ((float4*)A)[t] = ((const float4*)agg)[(size_t)row*32 + q];
}

// ---------------- final readout + global sum ----------------
__global__ void k_final(const float* __restrict__ A, const float* __restrict__ W1,
                        const float* __restrict__ b1, const float* __restrict__ W2,
                        const float* __restrict__ b2, const int* __restrict__ anum,
                        const float* __restrict__ escl, const float* __restrict__ eshf,
                        float* __restrict__ out){
    __shared__ float red[256];
    const int tid  = threadIdx.x;
    const int c    = tid & 127;
    const int half = tid >> 7;
    float b1c = b1[c];
    float w2c = W2[c];
    float b2v = b2[0];
    float tpart = 0.0f;
    const int npairs = NLOCAL/2;
    for (int p = blockIdx.x; p < npairs; p += gridDim.x){
        int a = 2*p + half;
        const float* h = A + (size_t)a*UNITS;
        float acc = b1c;
        for (int k = 0; k < UNITS; k++)
            acc = fmaf(h[k], W1[k*UNITS + c], acc);
        float hid = silu(acc);
        int z = anum[a];
        float sc = escl[z];
        tpart = fmaf(sc*hid, w2c, tpart);
        if (c == 0) tpart += sc*b2v + eshf[z];
    }
    red[tid] = tpart;
    __syncthreads();
    for (int s = 128; s > 0; s >>= 1){
        if (tid < s) red[tid] += red[tid + s];
        __syncthreads();
    }
    if (tid == 0) atomicAdd(out, red[0]);
}

extern "C" void kernel_launch(void* const* d_in, const int* in_sizes, int n_in,
                              void* d_out, int out_size, void* d_ws, size_t ws_size,
                              hipStream_t stream){
    const int*   anum  = (const int*)d_in[0];
    const float* pos   = (const float*)d_in[1];
    const float* cell  = (const float*)d_in[2];
    const float* pbc   = (const float*)d_in[3];
    const int*   esrc  = (const int*)d_in[4];
    const int*   edst  = (const int*)d_in[5];
    const int*   tbi   = (const int*)d_in[6];
    const int*   batch = (const int*)d_in[7];
    const int*   gmap  = (const int*)d_in[8];
    const float* embw  = (const float*)d_in[10];
    const float* encw  = (const float*)d_in[11];
    const float* encb  = (const float*)d_in[12];
    const float* tbaw  = (const float*)d_in[13];
    const float* tbab  = (const float*)d_in[14];
    const float* tbgw  = (const float*)d_in[15];
    const float* tbgb  = (const float*)d_in[16];
    const float* gewm  = (const float*)d_in[17];
    const float* gebm  = (const float*)d_in[18];
    const float* gewg  = (const float*)d_in[19];
    const float* gebg  = (const float*)d_in[20];
    const float* elew  = (const float*)d_in[21];
    const float* eleb  = (const float*)d_in[22];
    const float* gawm  = (const float*)d_in[23];
    const float* gabm  = (const float*)d_in[24];
    const float* gawg  = (const float*)d_in[25];
    const float* gabg  = (const float*)d_in[26];
    const float* elaw  = (const float*)d_in[27];
    const float* elab  = (const float*)d_in[28];
    const float* fw1   = (const float*)d_in[29];
    const float* fb1   = (const float*)d_in[30];
    const float* fw2   = (const float*)d_in[31];
    const float* fb2   = (const float*)d_in[32];
    const float* escl  = (const float*)d_in[33];
    const float* eshf  = (const float*)d_in[34];
    (void)in_sizes; (void)n_in; (void)out_size; (void)ws_size;

    float* ws    = (float*)d_ws;
    float* atomA = ws;                                   // NTOTAL*128
    float* agg   = atomA + (size_t)NTOTAL*UNITS;         // NLOCAL*128
    float* edgeE = agg   + (size_t)NLOCAL*UNITS;         // NEDGE*128
    float* evec  = edgeE + (size_t)NEDGE*UNITS;          // NEDGE*3
    float* elen  = evec  + (size_t)NEDGE*3;              // NEDGE
    float* rbf0  = elen  + (size_t)NEDGE;                // NEDGE*10
    float* tbout = rbf0  + (size_t)NEDGE*NRBF;           // NEDGE*9
    float* amlp  = tbout + (size_t)NEDGE*SBF;            // NLOCAL*9
    ushort* wpack = (ushort*)(amlp + (size_t)NLOCAL*SBF); // 3*4*49152 bf16

    float* out = (float*)d_out;
    hipMemsetAsync(out, 0, sizeof(float), stream);

    k_pack_w<<<(3*4*12*8*64 + 255)/256, 256, 0, stream>>>(gewm, gewg, gawm, gawg, wpack);
    k_edge_geom<<<(NEDGE+255)/256, 256, 0, stream>>>(pos, cell, pbc, esrc, edst, batch,
                                                     evec, elen, rbf0);
    k_embed<<<(NTOTAL*32+255)/256, 256, 0, stream>>>(anum, embw, atomA);
    k_edge_enc<<<(NEDGE*32+255)/256, 256, 0, stream>>>(rbf0, encw, encb, edgeE);

    const int gemm_blocks = (NEDGE+31)/32;
    for (int L = 0; L < NLAYERS; L++){
        const ushort* wpL = wpack + (size_t)L*4*49152;
        k_tb_mlp<<<(NLOCAL+255)/256, 256, 0, stream>>>(atomA,
            tbaw + (size_t)L*UNITS*SBF, tbab + (size_t)L*SBF, amlp);
        hipMemsetAsync(tbout, 0, (size_t)NEDGE*SBF*sizeof(float), stream);
        k_triple<<<(NTRIPLE+255)/256, 256, 0, stream>>>(evec, elen, esrc, tbi, amlp, tbout);
        hipMemcpyAsync(agg, atomA, (size_t)NLOCAL*UNITS*sizeof(float),
                       hipMemcpyDeviceToDevice, stream);
        k_gated<0><<<gemm_blocks, 256, 0, stream>>>(atomA, edgeE, esrc, edst,
            tbout, tbgw + (size_t)L*SBF*UNITS, tbgb + (size_t)L*UNITS,
            wpL + 0*49152, wpL + 1*49152,
            gebm + (size_t)L*UNITS, gebg + (size_t)L*UNITS,
            elew + (size_t)L*NRBF*UNITS, eleb + (size_t)L*UNITS, rbf0, nullptr);
        k_gated<1><<<gemm_blocks, 256, 0, stream>>>(atomA, edgeE, esrc, edst,
            nullptr, nullptr, nullptr,
            wpL + 2*49152, wpL + 3*49152,
            gabm + (size_t)L*UNITS, gabg + (size_t)L*UNITS,
            elaw + (size_t)L*NRBF*UNITS, elab + (size_t)L*UNITS, rbf0, agg);
        if (L < NLAYERS-1)
            k_expand<<<(NTOTAL*32+255)/256, 256, 0, stream>>>(agg, gmap, atomA);
    }
    k_final<<<1024, 256, 0, stream>>>(agg, fw1, fb1, fw2, fb2, anum, escl, eshf, out);
}

// Round 4
// 1621.260 us; speedup vs baseline: 3.6161x; 1.0964x over previous
//
#include <hip/hip_runtime.h>
#include <math.h>

#define UNITS   128
#define NRBF    10
#define SBF     9
#define NLAYERS 3
#define NELEM   95
#define NTOTAL  60000
#define NLOCAL  50000
#define NGHOST  10000
#define NEDGE   250000
#define NTRIPLE 1000000
#define CUTOFF  5.0f
#define TBCUT   4.0f
#define PI_F    3.14159265358979323846f

typedef __attribute__((ext_vector_type(8))) short short8;
typedef __attribute__((ext_vector_type(4))) float f32x4;

__device__ __forceinline__ float sigm(float x){ return 1.0f/(1.0f+expf(-x)); }
__device__ __forceinline__ float silu(float x){ return x/(1.0f+expf(-x)); }
__device__ __forceinline__ float polycut(float r){
    float q = r*(1.0f/TBCUT);
    float q2 = q*q, q3 = q2*q;
    float p = 1.0f - 6.0f*q2*q3 + 15.0f*q2*q2 - 10.0f*q3;
    return (r <= TBCUT) ? p : 0.0f;
}
__device__ __forceinline__ ushort f2bf(float x){
    unsigned u = __float_as_uint(x);
    unsigned r = (u + 0x7fffu + ((u>>16)&1u)) >> 16;
    return (ushort)r;
}
__device__ __forceinline__ void fma4s(float4& acc, float s, const float4& v){
    acc.x = fmaf(s, v.x, acc.x);
    acc.y = fmaf(s, v.y, acc.y);
    acc.z = fmaf(s, v.z, acc.z);
    acc.w = fmaf(s, v.w, acc.w);
}

// ---------------- edge geometry + rbf ----------------
__global__ void k_edge_geom(const float* __restrict__ pos, const float* __restrict__ cell,
                            const float* __restrict__ pbc, const int* __restrict__ src,
                            const int* __restrict__ dst, const int* __restrict__ batch,
                            float* __restrict__ evec, float* __restrict__ elen,
                            float* __restrict__ rbf0){
    int e = blockIdx.x*blockDim.x + threadIdx.x;
    if (e >= NEDGE) return;
    int s = src[e], d = dst[e];
    int b = batch[s];
    const float* C = cell + b*9;
    float p0 = pbc[e*3+0], p1 = pbc[e*3+1], p2 = pbc[e*3+2];
    float vx = pos[s*3+0] - (pos[d*3+0] + p0*C[0] + p1*C[3] + p2*C[6]);
    float vy = pos[s*3+1] - (pos[d*3+1] + p0*C[1] + p1*C[4] + p2*C[7]);
    float vz = pos[s*3+2] - (pos[d*3+2] + p0*C[2] + p1*C[5] + p2*C[8]);
    float r = sqrtf(vx*vx + vy*vy + vz*vz);
    evec[e*3+0] = vx; evec[e*3+1] = vy; evec[e*3+2] = vz;
    elen[e] = r;
    #pragma unroll
    for (int i = 0; i < NRBF; i++){
        float mu = (CUTOFF/(NRBF-1))*i;
        float dm = r - mu;
        rbf0[e*NRBF + i] = expf(-dm*dm*2.0f);
    }
}

// ---------------- atom embedding gather ----------------
__global__ void k_embed(const int* __restrict__ anum, const float* __restrict__ embw,
                        float* __restrict__ A){
    int t = blockIdx.x*blockDim.x + threadIdx.x;
    if (t >= NTOTAL*32) return;
    int a = t >> 5, q = t & 31;
    ((float4*)A)[t] = ((const float4*)embw)[anum[a]*32 + q];
}

// ---------------- edge encoding: E = rbf0 @ Wenc + benc ----------------
__global__ void k_edge_enc(const float* __restrict__ rbf0, const float* __restrict__ encw,
                           const float* __restrict__ encb, float* __restrict__ E){
    int t = blockIdx.x*blockDim.x + threadIdx.x;
    if (t >= NEDGE*32) return;
    int e = t >> 5, q = t & 31;
    float4 acc = ((const float4*)encb)[q];
    const float4* W4 = (const float4*)encw;
    #pragma unroll
    for (int r = 0; r < NRBF; r++){
        float rv = rbf0[e*NRBF + r];
        fma4s(acc, rv, W4[r*32 + q]);
    }
    ((float4*)E)[t] = acc;
}

// ---------------- pack gated-MLP weights into MFMA B-fragment layout ----------------
// layout: [L][mat(ge_m,ge_g,ga_m,ga_g)][kb:12][nt:8][lane:64][j:8] bf16
__global__ void k_pack_w(const float* __restrict__ gewm, const float* __restrict__ gewg,
                         const float* __restrict__ gawm, const float* __restrict__ gawg,
                         ushort* __restrict__ wp){
    int t = blockIdx.x*blockDim.x + threadIdx.x;
    if (t >= 3*4*12*8*64) return;
    int lane = t & 63;
    int nt   = (t>>6) & 7;
    int rest = t >> 9;
    int kb   = rest % 12;
    int r2   = rest / 12;
    int mat  = r2 & 3;
    int L    = r2 >> 2;
    const float* src;
    if      (mat == 0) src = gewm;
    else if (mat == 1) src = gewg;
    else if (mat == 2) src = gawm;
    else               src = gawg;
    src += (size_t)L*384*128;
    int n = nt*16 + (lane & 15);
    int kbase = kb*32 + (lane>>4)*8;
    ushort* dst = wp + (size_t)t*8;
    #pragma unroll
    for (int j = 0; j < 8; j++) dst[j] = f2bf(src[(size_t)(kbase+j)*128 + n]);
}

// ---------------- per-layer: atom sbf mlp ----------------
__global__ void k_tb_mlp(const float* __restrict__ A, const float* __restrict__ W,
                         const float* __restrict__ b, float* __restrict__ out){
    int a = blockIdx.x*blockDim.x + threadIdx.x;
    if (a >= NLOCAL) return;
    float acc[SBF];
    #pragma unroll
    for (int s = 0; s < SBF; s++) acc[s] = b[s];
    const float4* row4 = (const float4*)(A + (size_t)a*UNITS);
    for (int k4 = 0; k4 < 32; k4++){
        float4 v = row4[k4];
        const float* w = W + (k4*4)*SBF;
        #pragma unroll
        for (int s = 0; s < SBF; s++){
            acc[s] = fmaf(v.x, w[s],        acc[s]);
            acc[s] = fmaf(v.y, w[s+SBF],    acc[s]);
            acc[s] = fmaf(v.z, w[s+2*SBF],  acc[s]);
            acc[s] = fmaf(v.w, w[s+3*SBF],  acc[s]);
        }
    }
    #pragma unroll
    for (int s = 0; s < SBF; s++) out[a*SBF + s] = sigm(acc[s]);
}

// ---------------- per-layer: triples -> scatter into tb_out ----------------
__global__ void k_triple(const float* __restrict__ evec, const float* __restrict__ elen,
                         const int* __restrict__ esrc, const int* __restrict__ tbi,
                         const float* __restrict__ amlp, float* __restrict__ tb_out){
    int t = blockIdx.x*blockDim.x + threadIdx.x;
    if (t >= NTRIPLE) return;
    int ij = tbi[2*t], ik = tbi[2*t+1];
    float rij = elen[ij], rik = elen[ik];
    float cutij = polycut(rij), cutik = polycut(rik);
    float cc = cutij*cutik;
    if (cc == 0.0f) return;
    float ax = evec[ij*3+0], ay = evec[ij*3+1], az = evec[ij*3+2];
    float bx = evec[ik*3+0], by = evec[ik*3+1], bz = evec[ik*3+2];
    float dot = ax*bx + ay*by + az*bz;
    float c = dot/(rij*rik + 1e-12f);
    c = fminf(fmaxf(c, -1.0f + 1e-7f), 1.0f - 1e-7f);
    float a0 = 1.0f, a1 = c, a2 = 2.0f*c*c - 1.0f;
    float x = rik*(PI_F/TBCUT);
    float s1, c1;
    sincosf(x, &s1, &c1);
    float s2 = 2.0f*s1*c1;
    float s3 = s1*(3.0f - 4.0f*s1*s1);
    float inv = 1.0f/(rik + 1e-6f);
    float r0 = s1*inv, r1 = s2*inv, r2 = s3*inv;
    int ka = esrc[ik];
    const float* am = amlp + (size_t)ka*SBF;
    float* dst = tb_out + (size_t)ij*SBF;
    atomicAdd(dst+0, r0*a0*am[0]*cc);
    atomicAdd(dst+1, r0*a1*am[1]*cc);
    atomicAdd(dst+2, r0*a2*am[2]*cc);
    atomicAdd(dst+3, r1*a0*am[3]*cc);
    atomicAdd(dst+4, r1*a1*am[4]*cc);
    atomicAdd(dst+5, r1*a2*am[5]*cc);
    atomicAdd(dst+6, r2*a0*am[6]*cc);
    atomicAdd(dst+7, r2*a1*am[7]*cc);
    atomicAdd(dst+8, r2*a2*am[8]*cc);
}

// ---------------- fused per-layer gated blocks (ge + ga) via bf16 MFMA ----------------
// 32 edges/block, 4 waves. feat = [A[src] | A[dst] | E+tbgate] bf16 in LDS (stride 392).
// Phase 1: full-K ge GEMM + A-part (K 0..255) of ga GEMM in one loop.
// Epilogue 1: E_new = E_old + tbgate_f32 + silu(m)sigm(g)*el_e ; write global E + LDS bf16.
// Phase 2: remaining K 256..383 of ga GEMM on E_new.
// Epilogue 2: agg[src] += silu(m)sigm(g)*el_a (device atomics).
__global__ __launch_bounds__(256, 4)
void k_gated_fused(const float* __restrict__ A, float* __restrict__ E,
                   const int* __restrict__ esrc, const int* __restrict__ edst,
                   const float* __restrict__ tb_out, const float* __restrict__ tbg,
                   const float* __restrict__ tbb,
                   const ushort* __restrict__ WemP, const ushort* __restrict__ WegP,
                   const ushort* __restrict__ WamP, const ushort* __restrict__ WagP,
                   const float* __restrict__ bem, const float* __restrict__ beg,
                   const float* __restrict__ elew_, const float* __restrict__ eleb_,
                   const float* __restrict__ bam, const float* __restrict__ bag,
                   const float* __restrict__ elaw_, const float* __restrict__ elab_,
                   const float* __restrict__ rbf0, float* __restrict__ agg){
    __shared__ __align__(16) ushort feat_s[32*392];
    __shared__ float rbf_s[32][NRBF];
    __shared__ float tb_s[32][SBF];
    __shared__ int   src_s[32];
    __shared__ int   dst_s[32];

    const int tid = threadIdx.x;
    const int e0  = blockIdx.x*32;

    if (tid < 32){
        int e = min(e0 + tid, NEDGE-1);
        src_s[tid] = esrc[e];
        dst_s[tid] = edst[e];
        #pragma unroll
        for (int r = 0; r < NRBF; r++) rbf_s[tid][r] = rbf0[(size_t)e*NRBF + r];
        #pragma unroll
        for (int s = 0; s < SBF; s++) tb_s[tid][s] = tb_out[(size_t)e*SBF + s];
    }
    __syncthreads();

    const float4* A4   = (const float4*)A;
    const float4* E4   = (const float4*)E;
    const float4* tbg4 = (const float4*)tbg;
    const float4* tbb4 = (const float4*)tbb;

    // stage feat: 32 rows x 96 float4 -> bf16, 12 pieces/thread
    #pragma unroll
    for (int j = 0; j < 12; j++){
        int idx = j*256 + tid;
        int m   = idx/96;
        int k4  = idx - m*96;
        float4 v;
        if (k4 < 32){
            v = A4[(size_t)src_s[m]*32 + k4];
        } else if (k4 < 64){
            v = A4[(size_t)dst_s[m]*32 + (k4-32)];
        } else {
            int q = k4 - 64;
            int e = min(e0 + m, NEDGE-1);
            v = E4[(size_t)e*32 + q];
            float4 tacc = tbb4[q];
            #pragma unroll
            for (int s = 0; s < SBF; s++) fma4s(tacc, tb_s[m][s], tbg4[s*32 + q]);
            v.x += tacc.x; v.y += tacc.y; v.z += tacc.z; v.w += tacc.w;
        }
        ushort4 h;
        h.x = f2bf(v.x); h.y = f2bf(v.y); h.z = f2bf(v.z); h.w = f2bf(v.w);
        *(ushort4*)&feat_s[m*392 + k4*4] = h;
    }
    __syncthreads();

    const int lane = tid & 63;
    const int w    = tid >> 6;
    const int quad = lane >> 4;
    const int l15  = lane & 15;

    f32x4 zero4 = {0.f, 0.f, 0.f, 0.f};
    f32x4 acc_em[2][2], acc_eg[2][2], acc_am[2][2], acc_ag[2][2];
    #pragma unroll
    for (int mt = 0; mt < 2; mt++)
        #pragma unroll
        for (int ct = 0; ct < 2; ct++){
            acc_em[mt][ct] = zero4; acc_eg[mt][ct] = zero4;
            acc_am[mt][ct] = zero4; acc_ag[mt][ct] = zero4;
        }

    const ushort* a0p = feat_s + l15*392 + quad*8;
    const ushort* a1p = a0p + 16*392;

    // Phase 1: ge over K 0..383; ga over K 0..255 (A-part only)
    for (int ks = 0; ks < 12; ks++){
        short8 a0 = *(const short8*)(a0p + ks*32);
        short8 a1 = *(const short8*)(a1p + ks*32);
        #pragma unroll
        for (int ct = 0; ct < 2; ct++){
            int nt = w*2 + ct;
            size_t boff = ((size_t)(ks*8 + nt)*64 + lane)*8;
            short8 b_em = *(const short8*)(WemP + boff);
            short8 b_eg = *(const short8*)(WegP + boff);
            acc_em[0][ct] = __builtin_amdgcn_mfma_f32_16x16x32_bf16(a0, b_em, acc_em[0][ct], 0, 0, 0);
            acc_em[1][ct] = __builtin_amdgcn_mfma_f32_16x16x32_bf16(a1, b_em, acc_em[1][ct], 0, 0, 0);
            acc_eg[0][ct] = __builtin_amdgcn_mfma_f32_16x16x32_bf16(a0, b_eg, acc_eg[0][ct], 0, 0, 0);
            acc_eg[1][ct] = __builtin_amdgcn_mfma_f32_16x16x32_bf16(a1, b_eg, acc_eg[1][ct], 0, 0, 0);
            if (ks < 8){
                short8 b_am = *(const short8*)(WamP + boff);
                short8 b_ag = *(const short8*)(WagP + boff);
                acc_am[0][ct] = __builtin_amdgcn_mfma_f32_16x16x32_bf16(a0, b_am, acc_am[0][ct], 0, 0, 0);
                acc_am[1][ct] = __builtin_amdgcn_mfma_f32_16x16x32_bf16(a1, b_am, acc_am[1][ct], 0, 0, 0);
                acc_ag[0][ct] = __builtin_amdgcn_mfma_f32_16x16x32_bf16(a0, b_ag, acc_ag[0][ct], 0, 0, 0);
                acc_ag[1][ct] = __builtin_amdgcn_mfma_f32_16x16x32_bf16(a1, b_ag, acc_ag[1][ct], 0, 0, 0);
            }
        }
    }

    // Epilogue 1: edge update
    {
        float bmv[2], bgv[2], elbv[2], elwv[2][NRBF], tbbv[2], tbgv[2][SBF];
        #pragma unroll
        for (int ct = 0; ct < 2; ct++){
            int c = w*32 + ct*16 + l15;
            bmv[ct]  = bem[c];
            bgv[ct]  = beg[c];
            elbv[ct] = eleb_[c];
            #pragma unroll
            for (int r = 0; r < NRBF; r++) elwv[ct][r] = elew_[r*UNITS + c];
            tbbv[ct] = tbb[c];
            #pragma unroll
            for (int s = 0; s < SBF; s++) tbgv[ct][s] = tbg[s*UNITS + c];
        }
        // all phase-1 LDS reads are done (loop above); safe to overwrite E-region after barrier
        __syncthreads();
        #pragma unroll
        for (int mt = 0; mt < 2; mt++){
            #pragma unroll
            for (int r = 0; r < 4; r++){
                int ml = mt*16 + quad*4 + r;
                int e  = e0 + ml;
                if (e >= NEDGE) continue;
                #pragma unroll
                for (int ct = 0; ct < 2; ct++){
                    int c = w*32 + ct*16 + l15;
                    float xm = acc_em[mt][ct][r] + bmv[ct];
                    float xg = acc_eg[mt][ct][r] + bgv[ct];
                    float gate = silu(xm)*sigm(xg);
                    float el = elbv[ct];
                    #pragma unroll
                    for (int rr = 0; rr < NRBF; rr++) el = fmaf(rbf_s[ml][rr], elwv[ct][rr], el);
                    float tbc = tbbv[ct];
                    #pragma unroll
                    for (int s = 0; s < SBF; s++) tbc = fmaf(tb_s[ml][s], tbgv[ct][s], tbc);
                    float enew = E[(size_t)e*UNITS + c] + tbc + gate*el;
                    E[(size_t)e*UNITS + c] = enew;
                    feat_s[ml*392 + 256 + c] = f2bf(enew);
                }
            }
        }
    }
    __syncthreads();

    // Phase 2: ga over K 256..383 (updated E)
    for (int ks = 8; ks < 12; ks++){
        short8 a0 = *(const short8*)(a0p + ks*32);
        short8 a1 = *(const short8*)(a1p + ks*32);
        #pragma unroll
        for (int ct = 0; ct < 2; ct++){
            int nt = w*2 + ct;
            size_t boff = ((size_t)(ks*8 + nt)*64 + lane)*8;
            short8 b_am = *(const short8*)(WamP + boff);
            short8 b_ag = *(const short8*)(WagP + boff);
            acc_am[0][ct] = __builtin_amdgcn_mfma_f32_16x16x32_bf16(a0, b_am, acc_am[0][ct], 0, 0, 0);
            acc_am[1][ct] = __builtin_amdgcn_mfma_f32_16x16x32_bf16(a1, b_am, acc_am[1][ct], 0, 0, 0);
            acc_ag[0][ct] = __builtin_amdgcn_mfma_f32_16x16x32_bf16(a0, b_ag, acc_ag[0][ct], 0, 0, 0);
            acc_ag[1][ct] = __builtin_amdgcn_mfma_f32_16x16x32_bf16(a1, b_ag, acc_ag[1][ct], 0, 0, 0);
        }
    }

    // Epilogue 2: atom scatter
    {
        float bmv[2], bgv[2], elbv[2], elwv[2][NRBF];
        #pragma unroll
        for (int ct = 0; ct < 2; ct++){
            int c = w*32 + ct*16 + l15;
            bmv[ct]  = bam[c];
            bgv[ct]  = bag[c];
            elbv[ct] = elab_[c];
            #pragma unroll
            for (int r = 0; r < NRBF; r++) elwv[ct][r] = elaw_[r*UNITS + c];
        }
        #pragma unroll
        for (int mt = 0; mt < 2; mt++){
            #pragma unroll
            for (int r = 0; r < 4; r++){
                int ml = mt*16 + quad*4 + r;
                int e  = e0 + ml;
                if (e >= NEDGE) continue;
                #pragma unroll
                for (int ct = 0; ct < 2; ct++){
                    int c = w*32 + ct*16 + l15;
                    float xm = acc_am[mt][ct][r] + bmv[ct];
                    float xg = acc_ag[mt][ct][r] + bgv[ct];
                    float gate = silu(xm)*sigm(xg);
                    float el = elbv[ct];
                    #pragma unroll
                    for (int rr = 0; rr < NRBF; rr++) el = fmaf(rbf_s[ml][rr], elwv[ct][rr], el);
                    atomicAdd(&agg[(size_t)src_s[ml]*UNITS + c], gate*el);
                }
            }
        }
    }
}

// ---------------- ghost expansion ----------------
__global__ void k_expand(const float* __restrict__ agg, const int* __restrict__ gmap,
                         float* __restrict__ A){
    int t = blockIdx.x*blockDim.x + threadIdx.x;
    if (t >= NTOTAL*32) return;
    int i = t >> 5, q = t & 31;
    int row = (i < NLOCAL) ? i : gmap[i - NLOCAL];
    ((float4*)A)[t] = ((const float4*)agg)[(size_t)row*32 + q];
}

// ---------------- final readout + global sum ----------------
__global__ void k_final(const float* __restrict__ A, const float* __restrict__ W1,
                        const float* __restrict__ b1, const float* __restrict__ W2,
                        const float* __restrict__ b2, const int* __restrict__ anum,
                        const float* __restrict__ escl, const float* __restrict__ eshf,
                        float* __restrict__ out){
    __shared__ float red[256];
    const int tid  = threadIdx.x;
    const int c    = tid & 127;
    const int half = tid >> 7;
    float b1c = b1[c];
    float w2c = W2[c];
    float b2v = b2[0];
    float tpart = 0.0f;
    const int npairs = NLOCAL/2;
    for (int p = blockIdx.x; p < npairs; p += gridDim.x){
        int a = 2*p + half;
        const float* h = A + (size_t)a*UNITS;
        float acc = b1c;
        for (int k = 0; k < UNITS; k++)
            acc = fmaf(h[k], W1[k*UNITS + c], acc);
        float hid = silu(acc);
        int z = anum[a];
        float sc = escl[z];
        tpart = fmaf(sc*hid, w2c, tpart);
        if (c == 0) tpart += sc*b2v + eshf[z];
    }
    red[tid] = tpart;
    __syncthreads();
    for (int s = 128; s > 0; s >>= 1){
        if (tid < s) red[tid] += red[tid + s];
        __syncthreads();
    }
    if (tid == 0) atomicAdd(out, red[0]);
}

extern "C" void kernel_launch(void* const* d_in, const int* in_sizes, int n_in,
                              void* d_out, int out_size, void* d_ws, size_t ws_size,
                              hipStream_t stream){
    const int*   anum  = (const int*)d_in[0];
    const float* pos   = (const float*)d_in[1];
    const float* cell  = (const float*)d_in[2];
    const float* pbc   = (const float*)d_in[3];
    const int*   esrc  = (const int*)d_in[4];
    const int*   edst  = (const int*)d_in[5];
    const int*   tbi   = (const int*)d_in[6];
    const int*   batch = (const int*)d_in[7];
    const int*   gmap  = (const int*)d_in[8];
    const float* embw  = (const float*)d_in[10];
    const float* encw  = (const float*)d_in[11];
    const float* encb  = (const float*)d_in[12];
    const float* tbaw  = (const float*)d_in[13];
    const float* tbab  = (const float*)d_in[14];
    const float* tbgw  = (const float*)d_in[15];
    const float* tbgb  = (const float*)d_in[16];
    const float* gewm  = (const float*)d_in[17];
    const float* gebm  = (const float*)d_in[18];
    const float* gewg  = (const float*)d_in[19];
    const float* gebg  = (const float*)d_in[20];
    const float* elew  = (const float*)d_in[21];
    const float* eleb  = (const float*)d_in[22];
    const float* gawm  = (const float*)d_in[23];
    const float* gabm  = (const float*)d_in[24];
    const float* gawg  = (const float*)d_in[25];
    const float* gabg  = (const float*)d_in[26];
    const float* elaw  = (const float*)d_in[27];
    const float* elab  = (const float*)d_in[28];
    const float* fw1   = (const float*)d_in[29];
    const float* fb1   = (const float*)d_in[30];
    const float* fw2   = (const float*)d_in[31];
    const float* fb2   = (const float*)d_in[32];
    const float* escl  = (const float*)d_in[33];
    const float* eshf  = (const float*)d_in[34];
    (void)in_sizes; (void)n_in; (void)out_size; (void)ws_size;

    float* ws    = (float*)d_ws;
    float* atomA = ws;                                   // NTOTAL*128
    float* agg   = atomA + (size_t)NTOTAL*UNITS;         // NLOCAL*128
    float* edgeE = agg   + (size_t)NLOCAL*UNITS;         // NEDGE*128
    float* evec  = edgeE + (size_t)NEDGE*UNITS;          // NEDGE*3
    float* elen  = evec  + (size_t)NEDGE*3;              // NEDGE
    float* rbf0  = elen  + (size_t)NEDGE;                // NEDGE*10
    float* tbout = rbf0  + (size_t)NEDGE*NRBF;           // NEDGE*9
    float* amlp  = tbout + (size_t)NEDGE*SBF;            // NLOCAL*9
    ushort* wpack = (ushort*)(amlp + (size_t)NLOCAL*SBF); // 3*4*49152 bf16

    float* out = (float*)d_out;
    hipMemsetAsync(out, 0, sizeof(float), stream);

    k_pack_w<<<(3*4*12*8*64 + 255)/256, 256, 0, stream>>>(gewm, gewg, gawm, gawg, wpack);
    k_edge_geom<<<(NEDGE+255)/256, 256, 0, stream>>>(pos, cell, pbc, esrc, edst, batch,
                                                     evec, elen, rbf0);
    k_embed<<<(NTOTAL*32+255)/256, 256, 0, stream>>>(anum, embw, atomA);
    k_edge_enc<<<(NEDGE*32+255)/256, 256, 0, stream>>>(rbf0, encw, encb, edgeE);

    const int gemm_blocks = (NEDGE+31)/32;
    for (int L = 0; L < NLAYERS; L++){
        const ushort* wpL = wpack + (size_t)L*4*49152;
        k_tb_mlp<<<(NLOCAL+255)/256, 256, 0, stream>>>(atomA,
            tbaw + (size_t)L*UNITS*SBF, tbab + (size_t)L*SBF, amlp);
        hipMemsetAsync(tbout, 0, (size_t)NEDGE*SBF*sizeof(float), stream);
        k_triple<<<(NTRIPLE+255)/256, 256, 0, stream>>>(evec, elen, esrc, tbi, amlp, tbout);
        hipMemcpyAsync(agg, atomA, (size_t)NLOCAL*UNITS*sizeof(float),
                       hipMemcpyDeviceToDevice, stream);
        k_gated_fused<<<gemm_blocks, 256, 0, stream>>>(atomA, edgeE, esrc, edst,
            tbout, tbgw + (size_t)L*SBF*UNITS, tbgb + (size_t)L*UNITS,
            wpL + 0*49152, wpL + 1*49152, wpL + 2*49152, wpL + 3*49152,
            gebm + (size_t)L*UNITS, gebg + (size_t)L*UNITS,
            elew + (size_t)L*NRBF*UNITS, eleb + (size_t)L*UNITS,
            gabm + (size_t)L*UNITS, gabg + (size_t)L*UNITS,
            elaw + (size_t)L*NRBF*UNITS, elab + (size_t)L*UNITS,
            rbf0, agg);
        if (L < NLAYERS-1)
            k_expand<<<(NTOTAL*32+255)/256, 256, 0, stream>>>(agg, gmap, atomA);
    }
    k_final<<<1024, 256, 0, stream>>>(agg, fw1, fb1, fw2, fb2, anum, escl, eshf, out);
}